// Round 17
// baseline (113.114 us; speedup 1.0000x reference)
//
#include <hip/hip_runtime.h>
#include <stdint.h>

#define DEVI __device__ __forceinline__

typedef __attribute__((ext_vector_type(8))) short short8;
typedef __attribute__((ext_vector_type(4))) float f32x4;
typedef __attribute__((ext_vector_type(4))) uint32_t u32x4;

DEVI unsigned short f2bf(float f) {
    union { float f; uint32_t u; } v; v.f = f;
    return (unsigned short)((v.u + 0x7FFFu + ((v.u >> 16) & 1u)) >> 16);
}

DEVI uint32_t cvtpk_bf16(float a, float b) {
    uint32_t r;
    asm("v_cvt_pk_bf16_f32 %0, %1, %2" : "=v"(r) : "v"(a), "v"(b));
    return r;   // lo16 = bf16(a), hi16 = bf16(b)
}

// D[32:63] <-> S[0:31]
DEVI void perm32(uint32_t &a, uint32_t &b) {
    asm("v_permlane32_swap_b32 %0, %1" : "+v"(a), "+v"(b));
}
// D[16:31] <-> S[0:15], D[48:63] <-> S[32:47]
DEVI void perm16(uint32_t &a, uint32_t &b) {
    asm("v_permlane16_swap_b32 %0, %1" : "+v"(a), "+v"(b));
}

DEVI void gload16(const void* g, void* l) {
    __builtin_amdgcn_global_load_lds(
        (const __attribute__((address_space(1))) unsigned int*)g,
        (__attribute__((address_space(3))) unsigned int*)l, 16, 0, 0);
}

// ---------------- fused prep: x f32->bf16, w_in^T, w_out^T (independent jobs) ----------------
__global__ __launch_bounds__(256) void k_prep(
    const float* __restrict__ x, ushort* __restrict__ xb,
    const float* __restrict__ w_in, ushort* __restrict__ w_inT,
    const float* __restrict__ w_out, ushort* __restrict__ w_outT)
{
    const int bid = blockIdx.x;
    if (bid < 2048) {
        const int n4 = 4096 * 1024 / 4;
        int i = bid * 256 + threadIdx.x;
        const int stride = 2048 * 256;
        for (; i < n4; i += stride) {
            float4 v = ((const float4*)x)[i];
            ushort4 o;
            o.x = f2bf(v.x); o.y = f2bf(v.y); o.z = f2bf(v.z); o.w = f2bf(v.w);
            ((ushort4*)xb)[i] = o;
        }
        return;
    }
    const float* in; ushort* out; int R, C, t;
    if (bid < 5120) { in = w_in;  out = w_inT;  R = 1024; C = 3072; t = bid - 2048; }
    else            { in = w_out; out = w_outT; R = 1024; C = 1024; t = bid - 5120; }
    const int tpr = C / 32;
    const int c0 = (t % tpr) * 32, r0 = (t / tpr) * 32;
    __shared__ float tl[32][33];
    int lr = threadIdx.x >> 5, lc = threadIdx.x & 31;
    #pragma unroll
    for (int i = 0; i < 4; i++)
        tl[lr + 8*i][lc] = in[(size_t)(r0 + lr + 8*i)*C + c0 + lc];
    __syncthreads();
    #pragma unroll
    for (int i = 0; i < 4; i++)
        out[(size_t)(c0 + lr + 8*i)*R + r0 + lc] = f2bf(tl[lc][lr + 8*i]);
}

// ---------------- 8-phase 256x256 GEMM (m201 template port), MODE-0 epilogue ----------------
// 512 thr / 8 waves (2M x 4N), per-wave 128x64 out (acc[8][4]), BK=64, LDS 128 KB
// (A,B each 2buf x 256x64). Per phase: 12 ds_read_b128 + 2 staged 64-row units +
// barrier + lgkmcnt(0) + setprio + 16 MFMA + setprio + barrier. Counted vmcnt(2)
// only at K-tile entry (p0/p4); never drained in-loop (T3+T4). Stage slot table
// hazard-audited: each unit's LDS slot is read-finished >=1 barrier before issue.
__global__ __launch_bounds__(512, 2) void k_gemm8(
    const ushort* __restrict__ A, const ushort* __restrict__ Bt,
    const float* __restrict__ bias,
    ushort* __restrict__ oQ, ushort* __restrict__ oK, ushort* __restrict__ oV,
    int M, int N, int K, int S)
{
    __shared__ __align__(16) ushort As[2][256*64];
    __shared__ __align__(16) ushort Bs[2][256*64];
    const int tid = threadIdx.x;
    const int w = tid >> 6, l = tid & 63;
    const int wm = w >> 2, wn = w & 3;

    int lin = blockIdx.y * gridDim.x + blockIdx.x;
    int nwg = gridDim.x * gridDim.y;
    int swz = (lin & 7) * (nwg >> 3) + (lin >> 3);
    const int m0 = (swz / gridDim.x) * 256, n0 = (swz % gridDim.x) * 256;

    const int fr = l & 15, fg = l >> 4;
    const int lr8 = l >> 3;
    const int slot = (l & 7) ^ lr8;   // pre-swizzled k-slot (16B units)

    const int NT = K >> 6;            // 16 K-tiles
    f32x4 acc[8][4] = {};

    const ushort* Ab = A + (size_t)(m0 + w*8 + lr8) * K + slot*8;
    const ushort* Bb = Bt + (size_t)(n0 + w*8 + lr8) * K + slot*8;

    // stage one 64-row quarter q of K-tile kt into As/Bs[buf] (one gload call, 512 thr)
    auto stA = [&](int buf, int q, int kt) {
        gload16(Ab + (size_t)(q*64) * K + kt*64, &As[buf][(q*64 + w*8) * 64]);
    };
    auto stB = [&](int buf, int q, int kt) {
        gload16(Bb + (size_t)(q*64) * K + kt*64, &Bs[buf][(q*64 + w*8) * 64]);
    };

#define PHASE(BUF, IH, JH, STAGES) do {                                              \
    short8 af[4][2], bf[2][2];                                                       \
    _Pragma("unroll")                                                                \
    for (int ii = 0; ii < 4; ii++) {                                                 \
        int ra = wm*128 + ((IH)*4 + ii)*16 + fr;                                     \
        _Pragma("unroll")                                                            \
        for (int kk = 0; kk < 2; kk++)                                               \
            af[ii][kk] = *(const short8*)((const char*)As[BUF] + ra*128 +            \
                          ((kk*64 + fg*16) ^ ((ra & 7) << 4)));                      \
    }                                                                                \
    _Pragma("unroll")                                                                \
    for (int jj = 0; jj < 2; jj++) {                                                 \
        int rb = wn*64 + ((JH)*2 + jj)*16 + fr;                                      \
        _Pragma("unroll")                                                            \
        for (int kk = 0; kk < 2; kk++)                                               \
            bf[jj][kk] = *(const short8*)((const char*)Bs[BUF] + rb*128 +            \
                          ((kk*64 + fg*16) ^ ((rb & 7) << 4)));                      \
    }                                                                                \
    STAGES;                                                                          \
    __builtin_amdgcn_s_barrier();                                                    \
    asm volatile("s_waitcnt lgkmcnt(0)" ::: "memory");                               \
    __builtin_amdgcn_s_setprio(1);                                                   \
    _Pragma("unroll")                                                                \
    for (int kk = 0; kk < 2; kk++)                                                   \
        _Pragma("unroll")                                                            \
        for (int ii = 0; ii < 4; ii++)                                               \
            _Pragma("unroll")                                                        \
            for (int jj = 0; jj < 2; jj++)                                           \
                acc[(IH)*4 + ii][(JH)*2 + jj] = __builtin_amdgcn_mfma_f32_16x16x32_bf16( \
                    af[ii][kk], bf[jj][kk], acc[(IH)*4 + ii][(JH)*2 + jj], 0, 0, 0); \
    __builtin_amdgcn_s_setprio(0);                                                   \
    __builtin_amdgcn_s_barrier();                                                    \
} while (0)

    // prologue: A(0) q0-3, B(0) q0-3, A(1) q0,q2  (10 calls outstanding)
    stA(0, 0, 0); stA(0, 1, 0); stA(0, 2, 0); stA(0, 3, 0);
    stB(0, 0, 0); stB(0, 1, 0); stB(0, 2, 0); stB(0, 3, 0);
    stA(1, 0, 1); stA(1, 2, 1);

    const int ND = NT >> 1;
    for (int d = 0; d < ND; d++) {
        const int kt1 = 2*d + 1;
        const int kt2 = (2*d + 2 < NT) ? 2*d + 2 : 0;   // clamped tail (junk, uniform counts)
        const int kt3 = (2*d + 3 < NT) ? 2*d + 3 : 0;

        // ---- K-tile 2d from buf 0 ----
        asm volatile("s_waitcnt vmcnt(2)" ::: "memory");
        PHASE(0, 0, 0, { stB(1, 0, kt1); stB(1, 1, kt1); });
        PHASE(0, 0, 1, { stB(1, 2, kt1); stB(1, 3, kt1); });
        PHASE(0, 1, 0, { stA(1, 1, kt1); stA(1, 3, kt1); });
        PHASE(0, 1, 1, { stA(0, 0, kt2); stA(0, 2, kt2); });
        // ---- K-tile 2d+1 from buf 1 ----
        asm volatile("s_waitcnt vmcnt(2)" ::: "memory");
        PHASE(1, 0, 0, { stA(0, 1, kt2); stA(0, 3, kt2); });
        PHASE(1, 0, 1, { stB(0, 0, kt2); stB(0, 1, kt2); });
        PHASE(1, 1, 0, { stB(0, 2, kt2); stB(0, 3, kt2); });
        PHASE(1, 1, 1, { stA(1, 0, kt3); stA(1, 2, kt3); });
    }
#undef PHASE

    asm volatile("s_waitcnt vmcnt(0)" ::: "memory");   // drain junk stages before exit

    // MODE-0 epilogue: split -> Q (pre-scaled by log2e/8), K, V^T
    const int wr = wm*128, wc = wn*64;
    #pragma unroll
    for (int j = 0; j < 4; j++) {
        int n = n0 + wc + j*16 + fr;
        int region = n >> 10;            // 0=Q 1=K 2=V
        int h = (n & 1023) >> 6;
        int d = n & 63;
        float bv = bias[n];
        float scl = (region == 0) ? 0.18033688011112042f : 1.0f;
        #pragma unroll
        for (int i = 0; i < 8; i++) {
            int mrow = m0 + wr + i*16 + fg*4;
            int b = mrow >> 11;
            int s = mrow & 2047;
            if (region < 2) {
                ushort* dst = (region == 0 ? oQ : oK) + ((size_t)(b*16 + h)*S)*64 + (size_t)d;
                #pragma unroll
                for (int r = 0; r < 4; r++)
                    dst[(size_t)(s + r)*64] = f2bf((acc[i][j][r] + bv) * scl);
            } else {
                ushort* dst = oV + ((size_t)(b*16 + h)*64 + d)*S + s;
                ushort4 pk;
                pk.x = f2bf(acc[i][j][0] + bv);
                pk.y = f2bf(acc[i][j][1] + bv);
                pk.z = f2bf(acc[i][j][2] + bv);
                pk.w = f2bf(acc[i][j][3] + bv);
                *(ushort4*)dst = pk;
            }
        }
    }
}

// ---------------- GEMM (proven R10 structure) for out-proj: MODE 1, fp32 out ----------------
template<int MODE, int NJ>
__global__ __launch_bounds__(256, 2) void k_gemm(
    const ushort* __restrict__ A, const ushort* __restrict__ Bt,
    const float* __restrict__ bias,
    float* __restrict__ oF,
    int M, int N, int K)
{
    __shared__ __align__(16) ushort As[128*64];
    __shared__ __align__(16) ushort Bs[NJ*32*64];
    const int tid = threadIdx.x;
    const int w = tid >> 6, l = tid & 63;

    int lin = blockIdx.y * gridDim.x + blockIdx.x;
    int nwg = gridDim.x * gridDim.y;
    int swz = (lin & 7) * (nwg >> 3) + (lin >> 3);
    const int m0 = (swz / gridDim.x) * 128, n0 = (swz % gridDim.x) * (NJ*32);

    const int wr = (w >> 1) * 64, wc = (w & 1) * (NJ*16);
    const int fr = l & 15, fg = l >> 4;
    const int lr8 = l >> 3;
    const int slot = (l & 7) ^ lr8;

    f32x4 acc[4][NJ] = {};

    const ushort* Abase = A + (size_t)(m0 + w*32 + lr8) * K + slot*8;
    const ushort* Bbase = Bt + (size_t)(n0 + w*(NJ*8) + lr8) * K + slot*8;

    for (int k0 = 0; k0 < K; k0 += 64) {
        __syncthreads();
        #pragma unroll
        for (int i = 0; i < 4; i++)
            gload16(Abase + (size_t)(8*i)*K + k0, &As[(w*32 + 8*i)*64]);
        #pragma unroll
        for (int i = 0; i < NJ; i++)
            gload16(Bbase + (size_t)(8*i)*K + k0, &Bs[(w*(NJ*8) + 8*i)*64]);
        __syncthreads();
        #pragma unroll
        for (int kk = 0; kk < 2; kk++) {
            short8 af[4], bfr[NJ];
            #pragma unroll
            for (int i = 0; i < 4; i++) {
                int ra = wr + i*16 + fr;
                af[i] = *(const short8*)((const char*)As + ra*128 + ((kk*64 + fg*16) ^ ((ra & 7) << 4)));
            }
            #pragma unroll
            for (int j = 0; j < NJ; j++) {
                int rb = wc + j*16 + fr;
                bfr[j] = *(const short8*)((const char*)Bs + rb*128 + ((kk*64 + fg*16) ^ ((rb & 7) << 4)));
            }
            #pragma unroll
            for (int i = 0; i < 4; i++)
                #pragma unroll
                for (int j = 0; j < NJ; j++)
                    acc[i][j] = __builtin_amdgcn_mfma_f32_16x16x32_bf16(af[i], bfr[j], acc[i][j], 0, 0, 0);
        }
    }

    #pragma unroll
    for (int j = 0; j < NJ; j++) {
        int n = n0 + wc + j*16 + fr;
        float bv = bias[n];
        #pragma unroll
        for (int i = 0; i < 4; i++) {
            int mrow = m0 + wr + i*16 + fg*4;
            #pragma unroll
            for (int r = 0; r < 4; r++)
                oF[(size_t)(mrow + r)*N + n] = acc[i][j][r] + bv;
        }
    }
}

// ---------------- flash attention (causal), swapped-operand, no-max, P-in-register ----------------
// (R4/R10-proven configuration: 42.5 us)
__global__ __launch_bounds__(128, 2) void k_attn(
    const ushort* __restrict__ Q,   // [B,H,S,64] (pre-scaled by log2e/8)
    const ushort* __restrict__ Kb,  // [B,H,S,64]
    const ushort* __restrict__ Vt,  // [B,H,64,S]
    ushort* __restrict__ O,         // [B*S][1024] bf16
    int S)
{
    __shared__ __align__(16) ushort Kt[2][64*64];
    __shared__ __align__(16) ushort Vs[2][64*64];

    const int tid = threadIdx.x, w = tid >> 6, l = tid & 63;
    const int bid = blockIdx.x;
    const int half = bid >> 9;
    const int r_ = bid & 511;
    const int h = r_ & 15, b = (r_ >> 4) & 1, p = r_ >> 5;
    const int qt = half ? p : (31 - p);
    const int bh = b * 16 + h;
    const int qw = qt * 64 + w * 32;
    const int fr = l & 15, fg = l >> 4;

    short8 qf[2][2];
    {
        const ushort* qp = Q + ((size_t)bh*S + qw + fr)*64 + fg*8;
        qf[0][0] = *(const short8*)(qp);
        qf[0][1] = *(const short8*)(qp + 32);
        qf[1][0] = *(const short8*)(qp + 16*64);
        qf[1][1] = *(const short8*)(qp + 16*64 + 32);
    }

    float l_[2] = {0.f, 0.f};
    f32x4 o_[2][4] = {};

    const int lr8 = l >> 3;
    const int slot = (l & 7) ^ lr8;
    const ushort* Ksrc = Kb + (size_t)bh*S*64;
    const ushort* Vsrc = Vt + (size_t)bh*64*S;

    const int nt = qt + 1;

    auto stage = [&](int buf, int j0) {
        #pragma unroll
        for (int i = 0; i < 4; i++) {
            int rb = w*32 + i*8;
            gload16(Ksrc + (size_t)(j0 + rb + lr8)*64 + slot*8, &Kt[buf][rb*64]);
            gload16(Vsrc + (size_t)(rb + lr8)*S + j0 + slot*8, &Vs[buf][rb*64]);
        }
    };

    stage(0, 0);
    __syncthreads();
    int cur = 0;

    for (int jt = 0; jt < nt; jt++) {
        const int j0 = jt * 64;
        if (jt + 1 < nt) stage(cur ^ 1, j0 + 64);

        f32x4 sa[2][4] = {};
        __builtin_amdgcn_s_setprio(1);
        #pragma unroll
        for (int kk = 0; kk < 2; kk++) {
            short8 kf[4];
            #pragma unroll
            for (int f = 0; f < 4; f++) {
                int row = f*16 + fr;
                kf[f] = *(const short8*)((const char*)Kt[cur] + row*128 + ((kk*64 + fg*16) ^ ((row & 7) << 4)));
            }
            #pragma unroll
            for (int t = 0; t < 2; t++)
                #pragma unroll
                for (int f = 0; f < 4; f++)
                    sa[t][f] = __builtin_amdgcn_mfma_f32_16x16x32_bf16(kf[f], qf[t][kk], sa[t][f], 0, 0, 0);
        }
        __builtin_amdgcn_s_setprio(0);

        if (jt == nt - 1) {
            #pragma unroll
            for (int t = 0; t < 2; t++) {
                int qg = qw + t*16 + fr;
                #pragma unroll
                for (int f = 0; f < 4; f++) {
                    int base = j0 + f*16 + fg*4 - qg;
                    #pragma unroll
                    for (int r = 0; r < 4; r++)
                        if (base + r > 0) sa[t][f][r] = -1e30f;
                }
            }
        }

        uint32_t cw[2][4][2];
        #pragma unroll
        for (int t = 0; t < 2; t++)
            #pragma unroll
            for (int f = 0; f < 4; f++) {
                float p0 = __builtin_amdgcn_exp2f(sa[t][f][0]);
                float p1 = __builtin_amdgcn_exp2f(sa[t][f][1]);
                float p2 = __builtin_amdgcn_exp2f(sa[t][f][2]);
                float p3 = __builtin_amdgcn_exp2f(sa[t][f][3]);
                l_[t] += (p0 + p1) + (p2 + p3);
                cw[t][f][0] = cvtpk_bf16(p0, p1);
                cw[t][f][1] = cvtpk_bf16(p2, p3);
            }

        __builtin_amdgcn_s_setprio(1);
        #pragma unroll
        for (int kk = 0; kk < 2; kk++) {
            short8 pf[2];
            #pragma unroll
            for (int t = 0; t < 2; t++) {
                uint32_t a0 = cw[t][2*kk][0], b0 = cw[t][2*kk + 1][0];
                perm32(a0, b0); perm16(a0, b0);
                uint32_t a1 = cw[t][2*kk][1], b1 = cw[t][2*kk + 1][1];
                perm32(a1, b1); perm16(a1, b1);
                u32x4 uw; uw[0] = a0; uw[1] = a1; uw[2] = b0; uw[3] = b1;
                pf[t] = __builtin_bit_cast(short8, uw);
            }
            #pragma unroll
            for (int f = 0; f < 4; f++) {
                int row = f*16 + fr;
                short8 vf = *(const short8*)((const char*)Vs[cur] + row*128 + ((kk*64 + fg*16) ^ ((row & 7) << 4)));
                #pragma unroll
                for (int t = 0; t < 2; t++)
                    o_[t][f] = __builtin_amdgcn_mfma_f32_16x16x32_bf16(vf, pf[t], o_[t][f], 0, 0, 0);
            }
        }
        __builtin_amdgcn_s_setprio(0);

        __syncthreads();
        cur ^= 1;
    }

    #pragma unroll
    for (int t = 0; t < 2; t++) {
        l_[t] += __shfl_xor(l_[t], 16);
        l_[t] += __shfl_xor(l_[t], 32);
    }

    #pragma unroll
    for (int t = 0; t < 2; t++) {
        float inv = 1.0f / l_[t];
        int qg = qw + t*16 + fr;
        #pragma unroll
        for (int f = 0; f < 4; f++) {
            ushort4 pk;
            pk.x = f2bf(o_[t][f][0] * inv);
            pk.y = f2bf(o_[t][f][1] * inv);
            pk.z = f2bf(o_[t][f][2] * inv);
            pk.w = f2bf(o_[t][f][3] * inv);
            *(ushort4*)&O[((size_t)(b*S + qg))*1024 + h*64 + f*16 + fg*4] = pk;
        }
    }
}

extern "C" void kernel_launch(void* const* d_in, const int* in_sizes, int n_in,
                              void* d_out, int out_size, void* d_ws, size_t ws_size,
                              hipStream_t stream)
{
    const float* x     = (const float*)d_in[0];
    const float* w_in  = (const float*)d_in[1];
    const float* b_in  = (const float*)d_in[2];
    const float* w_out = (const float*)d_in[3];
    const float* b_out = (const float*)d_in[4];
    float* out = (float*)d_out;

    const int B = 2, S = 2048, D = 1024, H = 16;
    const int M = B * S;  // 4096

    if (ws_size < (40u << 20)) return;
    char* ws = (char*)d_ws;
    ushort* xb     = (ushort*)(ws);              // 8MB: x bf16, later reused as attn_out
    ushort* w_inT  = (ushort*)(ws + (8u << 20)); // 6MB
    ushort* w_outT = (ushort*)(ws + (14u << 20));// 2MB
    ushort* qb     = (ushort*)(ws + (16u << 20));// 8MB
    ushort* kb     = (ushort*)(ws + (24u << 20));// 8MB
    ushort* vtb    = (ushort*)(ws + (32u << 20));// 8MB

    k_prep<<<6144, 256, 0, stream>>>(x, xb, w_in, w_inT, w_out, w_outT);
    // gemm0: 8-phase 256x256 pipeline (192 blocks, 512 thr)
    k_gemm8<<<dim3(3*D/256, M/256), 512, 0, stream>>>(xb, w_inT, b_in, qb, kb, vtb, M, 3*D, D, S);
    k_attn<<<1024, 128, 0, stream>>>(qb, kb, vtb, xb, S);
    k_gemm<1,2><<<dim3(D/64, M/128), 256, 0, stream>>>(xb, w_outT, b_out, out, M, D, D);
}